// Round 7
// baseline (4361.238 us; speedup 1.0000x reference)
//
#include <hip/hip_runtime.h>
#include <hip/hip_bf16.h>

// MimiEuclideanCodebook — single MFMA scan (per-tile thresholds) + np-bit-exact
// rescore with fused gather.
// scan (bf16 MFMA): per row, per 128-col tile, capture codes with
//   d2a <= tilemin + DELTA  (provably contains the exact argmin: DELTA >= 2*err).
// rescore: np-exact OpenBLAS-style fp32 FMA chain on candidates, lex-min
// (value, idx) — order-independent => deterministic. Fallback (cnt > SLOTS):
// full-row exact scan. Gather fused (8 lanes x 32 cols per row).

typedef float f32x4 __attribute__((ext_vector_type(4)));
typedef short s16x4 __attribute__((ext_vector_type(4)));
typedef short s16x8 __attribute__((ext_vector_type(8)));

#define D_DIM 256
#define N_ROWS 65536
#define K_CODES 2048
#define VQ_EPS 1e-5f
#define DELTA 1.0f
#define SLOTS 64

__device__ __forceinline__ short bf16s(float f) {
    __hip_bfloat16 h = __float2bfloat16(f);
    return __builtin_bit_cast(short, h);
}

// ---------------- prep: embed = embed_sum / clip(usage) -----------------------
__global__ void prep_embed(const float* __restrict__ es, const float* __restrict__ us,
                           float* __restrict__ embed) {
    int i = blockIdx.x * 256 + threadIdx.x;               // 524288
    int k = i >> 8;
    float u = fmaxf(us[k], VQ_EPS);
    embed[i] = es[i] / u;                                 // IEEE div == np bitwise
}

// numpy pairwise sum of squares over 256 (verified round 4)
__device__ __forceinline__ void np_sumsq_16lane(const float* a, float* out, int g) {
#pragma clang fp contract(off)
    int j = g & 7, h = g >> 3;
    const float* p = a + h * 128;
    float t = p[j];
    float r = t * t;
#pragma unroll
    for (int i = 1; i < 16; ++i) { float v = p[j + 8 * i]; r += v * v; }
    r += __shfl_xor(r, 1);
    r += __shfl_xor(r, 2);
    r += __shfl_xor(r, 4);
    float other = __shfl_xor(r, 8);
    if (g == 0) *out = r + other;
}

__global__ void prep_e2(const float* __restrict__ embed, float* __restrict__ e2) {
    int gid = blockIdx.x * 256 + threadIdx.x;             // 2048 * 16
    int k = gid >> 4;
    np_sumsq_16lane(embed + k * D_DIM, e2 + k, threadIdx.x & 15);
}

__global__ void prep_x2(const float* __restrict__ x, float* __restrict__ x2,
                        unsigned* __restrict__ counts) {
    int gid = blockIdx.x * 256 + threadIdx.x;             // 65536 * 16
    int r = gid >> 4;
    int g = threadIdx.x & 15;
    np_sumsq_16lane(x + r * D_DIM, x2 + r, g);
    if (g == 1) counts[r] = 0u;                           // re-init every call
}

// ---------------- bf16 MFMA scan: per-tile threshold candidate capture --------
__launch_bounds__(256, 2)
__global__ void vq_scan(const float* __restrict__ x, const float* __restrict__ embed,
                        const float* __restrict__ e2, const float* __restrict__ x2,
                        unsigned* __restrict__ counts, unsigned short* __restrict__ cands) {
    __shared__ short lA[128][40];                         // bf16 bits, stride 40
    __shared__ short lB[128][40];

    const int mt = blockIdx.x >> 4, nt = blockIdx.x & 15;
    const int m_base = mt * 128, n_base = nt * 128;
    const int tid = threadIdx.x, lane = tid & 63, wid = tid >> 6;
    const int wm = wid >> 1, wn = wid & 1;                // 2x2 waves, 64x64 each
    const int rb = wm * 64, cb = wn * 64;
    const int l15 = lane & 15, lg = lane >> 4;
    const int srow = tid >> 1, sseg = tid & 1;            // staging: row, 16-float half

    f32x4 acc[4][4];
#pragma unroll
    for (int m = 0; m < 4; ++m)
#pragma unroll
        for (int n = 0; n < 4; ++n) { f32x4 z = {0.f, 0.f, 0.f, 0.f}; acc[m][n] = z; }

    f32x4 rA[4], rB[4];
    auto gload = [&](int kc) {
#pragma unroll
        for (int v = 0; v < 4; ++v)
            rA[v] = *(const f32x4*)&x[(m_base + srow) * D_DIM + kc * 32 + sseg * 16 + v * 4];
#pragma unroll
        for (int v = 0; v < 4; ++v)
            rB[v] = *(const f32x4*)&embed[(n_base + srow) * D_DIM + kc * 32 + sseg * 16 + v * 4];
    };
    auto swrite = [&]() {
#pragma unroll
        for (int v = 0; v < 4; ++v) {
            s16x4 a, b;
#pragma unroll
            for (int j = 0; j < 4; ++j) { a[j] = bf16s(rA[v][j]); b[j] = bf16s(rB[v][j]); }
            *(s16x4*)&lA[srow][sseg * 16 + v * 4] = a;
            *(s16x4*)&lB[srow][sseg * 16 + v * 4] = b;
        }
    };
    auto compute = [&]() {
        s16x8 af[4], bf[4];
#pragma unroll
        for (int m = 0; m < 4; ++m)
            af[m] = *(const s16x8*)&lA[rb + m * 16 + l15][lg * 8];
#pragma unroll
        for (int n = 0; n < 4; ++n)
            bf[n] = *(const s16x8*)&lB[cb + n * 16 + l15][lg * 8];
#pragma unroll
        for (int m = 0; m < 4; ++m)
#pragma unroll
            for (int n = 0; n < 4; ++n)
                acc[m][n] = __builtin_amdgcn_mfma_f32_16x16x32_bf16(af[m], bf[n], acc[m][n], 0, 0, 0);
    };

    gload(0);
#pragma unroll 1
    for (int kc = 0; kc < 8; ++kc) {
        __syncthreads();                                  // prev compute done
        swrite();
        __syncthreads();                                  // LDS visible
        if (kc < 7) gload(kc + 1);
        compute();
    }

    // epilogue: d2a = (x2 - 2*xe_a) + e2; per-row TILE min over this 128-col
    // tile (16-lane butterfly); capture d2a <= tilemin + DELTA.
    // C/D layout (m89-verified): col = lane&15, row = (lane>>4)*4 + reg
    const int grow0 = m_base + rb + lg * 4;               // + m*16 + j
    const int gcol0 = n_base + cb + l15;                  // + n*16
    float e2v[4];
#pragma unroll
    for (int n = 0; n < 4; ++n) e2v[n] = e2[gcol0 + n * 16];

#pragma unroll
    for (int m = 0; m < 4; ++m) {
#pragma unroll
        for (int j = 0; j < 4; ++j) {
            int gr = grow0 + m * 16 + j;
            float x2v = x2[gr];
            float d2v[4];
            float mn = __builtin_inff();
#pragma unroll
            for (int n = 0; n < 4; ++n) {
                d2v[n] = (x2v - 2.0f * acc[m][n][j]) + e2v[n];
                mn = fminf(mn, d2v[n]);
            }
#pragma unroll
            for (int s = 1; s < 16; s <<= 1) mn = fminf(mn, __shfl_xor(mn, s));
            float thr = mn + DELTA;
#pragma unroll
            for (int n = 0; n < 4; ++n) {
                if (d2v[n] <= thr) {
                    unsigned p = atomicAdd(&counts[gr], 1u);
                    if (p < SLOTS) cands[gr * SLOTS + p] = (unsigned short)(gcol0 + n * 16);
                }
            }
        }
    }
}

// ------- np-exact rescore (8 rows/wave, 8 lanes/row) + fused gather -----------
__launch_bounds__(256, 4)
__global__ void vq_rescore(const float* __restrict__ x, const float* __restrict__ embed,
                           const float* __restrict__ e2, const float* __restrict__ x2,
                           const unsigned* __restrict__ counts,
                           const unsigned short* __restrict__ cands,
                           const float* __restrict__ es, const float* __restrict__ us,
                           float* __restrict__ out) {
    const int tid = threadIdx.x;
    const int r = blockIdx.x * 32 + (tid >> 3);           // 32 rows per block
    const int sl = tid & 7;                               // 8 lanes per row
    const unsigned cnt = counts[r];

    float bv = __builtin_inff();
    int bi = 0x7FFFFFFF;

    auto dot_d2 = [&](int code) -> float {
        float t = 0.0f;
#pragma unroll 8
        for (int k4 = 0; k4 < 64; ++k4) {                 // single chain, k ascending
            f32x4 a4 = *(const f32x4*)&x[r * D_DIM + k4 * 4];
            f32x4 e4 = *(const f32x4*)&embed[code * D_DIM + k4 * 4];
            t = __builtin_fmaf(a4[0], e4[0], t);
            t = __builtin_fmaf(a4[1], e4[1], t);
            t = __builtin_fmaf(a4[2], e4[2], t);
            t = __builtin_fmaf(a4[3], e4[3], t);
        }
        return (x2[r] - 2.0f * t) + e2[code];             // np op order
    };

    if (cnt <= SLOTS) {
        for (int slot = sl; slot < (int)cnt; slot += 8) {
            int code = (int)cands[r * SLOTS + slot];
            float d2 = dot_d2(code);
            if (d2 < bv || (d2 == bv && code < bi)) { bv = d2; bi = code; }
        }
    } else {
        // overflow fallback: exact scan of ALL codes (ascending per lane)
#pragma unroll 1
        for (int q = 0; q < 256; ++q) {
            int code = q * 8 + sl;
            float d2 = dot_d2(code);
            if (d2 < bv || (d2 == bv && code < bi)) { bv = d2; bi = code; }
        }
    }
#pragma unroll
    for (int s = 1; s < 8; s <<= 1) {                     // 8-lane lex allreduce
        float ov = __shfl_xor(bv, s);
        int oi = __shfl_xor(bi, s);
        if (ov < bv || (ov == bv && oi < bi)) { bv = ov; bi = oi; }
    }
    if (sl == 0) out[r] = (float)bi;

    // fused gather: quantized[r] = es[bi]/max(us[bi],eps); 8 lanes x 32 cols
    float u = fmaxf(us[bi], VQ_EPS);
    float* outq = out + N_ROWS;
#pragma unroll
    for (int v = 0; v < 8; ++v) {
        f32x4 w = *(const f32x4*)&es[bi * D_DIM + sl * 32 + v * 4];
        f32x4 o;
#pragma unroll
        for (int j = 0; j < 4; ++j) o[j] = w[j] / u;      // IEEE div == np bitwise
        *(f32x4*)&outq[r * D_DIM + sl * 32 + v * 4] = o;
    }
}

extern "C" void kernel_launch(void* const* d_in, const int* in_sizes, int n_in,
                              void* d_out, int out_size, void* d_ws, size_t ws_size,
                              hipStream_t stream) {
    const float* x = (const float*)d_in[0];               // [65536, 256]
    const float* es = (const float*)d_in[1];              // [2048, 256]
    const float* us = (const float*)d_in[2];              // [2048]
    float* out = (float*)d_out;

    char* w = (char*)d_ws;                                // total 11,018,240 B
    float* embed          = (float*)(w);                  //  2,097,152
    float* e2             = (float*)(w + 2097152);        //      8,192
    float* x2             = (float*)(w + 2105344);        //    262,144
    unsigned* counts      = (unsigned*)(w + 2367488);     //    262,144
    unsigned short* cands = (unsigned short*)(w + 2629632);// 8,388,608 (SLOTS=64)

    hipLaunchKernelGGL(prep_embed, dim3(2048), dim3(256), 0, stream, es, us, embed);
    hipLaunchKernelGGL(prep_e2, dim3(128), dim3(256), 0, stream, embed, e2);
    hipLaunchKernelGGL(prep_x2, dim3(4096), dim3(256), 0, stream, x, x2, counts);
    hipLaunchKernelGGL(vq_scan, dim3(8192), dim3(256), 0, stream,
                       x, embed, e2, x2, counts, cands);
    hipLaunchKernelGGL(vq_rescore, dim3(2048), dim3(256), 0, stream,
                       x, embed, e2, x2, counts, cands, es, us, out);
}

// Round 8
// 536.616 us; speedup vs baseline: 8.1273x; 8.1273x over previous
//
#include <hip/hip_runtime.h>
#include <hip/hip_bf16.h>

// MimiEuclideanCodebook — single bf16-MFMA scan (per-tile min + ballot-compacted
// candidate capture, NO atomics) + np-bit-exact rescore with global-min tile
// filter and fused gather.
// Guarantee: any code with d2a <= gm + DELTA is captured in its own tile's list
// (tilemin_T >= gm). Tiles with tilemin > gm + DELTA cannot hold the argmin
// (DELTA >= 2*err for near-min codes). Qualifying tile overflow (count > CAP)
// -> exact rescan of that 128-code tile only. All decisions use the round-4-
// verified np-exact fp32 FMA chain; ties lex-(value, index).

typedef float f32x4 __attribute__((ext_vector_type(4)));
typedef short s16x4 __attribute__((ext_vector_type(4)));
typedef short s16x8 __attribute__((ext_vector_type(8)));

#define D_DIM 256
#define N_ROWS 65536
#define K_CODES 2048
#define VQ_EPS 1e-5f
#define DELTA 1.0f
#define CAP 8

__device__ __forceinline__ short bf16s(float f) {
    __hip_bfloat16 h = __float2bfloat16(f);
    return __builtin_bit_cast(short, h);
}

// ---------------- prep: embed = embed_sum / clip(usage) -----------------------
__global__ void prep_embed(const float* __restrict__ es, const float* __restrict__ us,
                           float* __restrict__ embed) {
    int i = blockIdx.x * 256 + threadIdx.x;               // 524288
    int k = i >> 8;
    float u = fmaxf(us[k], VQ_EPS);
    embed[i] = es[i] / u;                                 // IEEE div == np bitwise
}

// numpy pairwise sum of squares over 256 (verified round 4)
__device__ __forceinline__ void np_sumsq_16lane(const float* a, float* out, int g) {
#pragma clang fp contract(off)
    int j = g & 7, h = g >> 3;
    const float* p = a + h * 128;
    float t = p[j];
    float r = t * t;
#pragma unroll
    for (int i = 1; i < 16; ++i) { float v = p[j + 8 * i]; r += v * v; }
    r += __shfl_xor(r, 1);
    r += __shfl_xor(r, 2);
    r += __shfl_xor(r, 4);
    float other = __shfl_xor(r, 8);
    if (g == 0) *out = r + other;
}

__global__ void prep_e2(const float* __restrict__ embed, float* __restrict__ e2) {
    int gid = blockIdx.x * 256 + threadIdx.x;             // 2048 * 16
    int k = gid >> 4;
    np_sumsq_16lane(embed + k * D_DIM, e2 + k, threadIdx.x & 15);
}

__global__ void prep_x2(const float* __restrict__ x, float* __restrict__ x2) {
    int gid = blockIdx.x * 256 + threadIdx.x;             // 65536 * 16
    int r = gid >> 4;
    np_sumsq_16lane(x + r * D_DIM, x2 + r, threadIdx.x & 15);
}

// --------- bf16 MFMA scan: per-(row,tile) min + <=CAP candidates --------------
// Wave layout: each wave owns 32 rows x full 128-col tile (acc[2][8]).
__launch_bounds__(256, 2)
__global__ void vq_scan(const float* __restrict__ x, const float* __restrict__ embed,
                        const float* __restrict__ e2, const float* __restrict__ x2,
                        float* __restrict__ tilemin, unsigned char* __restrict__ counts,
                        unsigned char* __restrict__ cands) {
    __shared__ short lA[128][40];                         // bf16 bits, stride 40
    __shared__ short lB[128][40];

    const int mt = blockIdx.x >> 4, nt = blockIdx.x & 15;
    const int m_base = mt * 128, n_base = nt * 128;
    const int tid = threadIdx.x, lane = tid & 63, wid = tid >> 6;
    const int rb = wid * 32;                              // wave: rows rb..rb+31, all 128 cols
    const int l15 = lane & 15, lg = lane >> 4;
    const int srow = tid >> 1, sseg = tid & 1;            // staging: row, 16-float half

    f32x4 acc[2][8];
#pragma unroll
    for (int m = 0; m < 2; ++m)
#pragma unroll
        for (int n = 0; n < 8; ++n) { f32x4 z = {0.f, 0.f, 0.f, 0.f}; acc[m][n] = z; }

    f32x4 rA[4], rB[4];
    auto gload = [&](int kc) {
#pragma unroll
        for (int v = 0; v < 4; ++v)
            rA[v] = *(const f32x4*)&x[(m_base + srow) * D_DIM + kc * 32 + sseg * 16 + v * 4];
#pragma unroll
        for (int v = 0; v < 4; ++v)
            rB[v] = *(const f32x4*)&embed[(n_base + srow) * D_DIM + kc * 32 + sseg * 16 + v * 4];
    };
    auto swrite = [&]() {
#pragma unroll
        for (int v = 0; v < 4; ++v) {
            s16x4 a, b;
#pragma unroll
            for (int j = 0; j < 4; ++j) { a[j] = bf16s(rA[v][j]); b[j] = bf16s(rB[v][j]); }
            *(s16x4*)&lA[srow][sseg * 16 + v * 4] = a;
            *(s16x4*)&lB[srow][sseg * 16 + v * 4] = b;
        }
    };
    auto compute = [&]() {
        s16x8 af[2], bf[8];
#pragma unroll
        for (int m = 0; m < 2; ++m)
            af[m] = *(const s16x8*)&lA[rb + m * 16 + l15][lg * 8];
#pragma unroll
        for (int n = 0; n < 8; ++n)
            bf[n] = *(const s16x8*)&lB[n * 16 + l15][lg * 8];
#pragma unroll
        for (int m = 0; m < 2; ++m)
#pragma unroll
            for (int n = 0; n < 8; ++n)
                acc[m][n] = __builtin_amdgcn_mfma_f32_16x16x32_bf16(af[m], bf[n], acc[m][n], 0, 0, 0);
    };

    gload(0);
#pragma unroll 1
    for (int kc = 0; kc < 8; ++kc) {
        __syncthreads();                                  // prev compute done
        swrite();
        __syncthreads();                                  // LDS visible
        if (kc < 7) gload(kc + 1);
        compute();
    }

    // epilogue: d2a = (x2 - 2*xe_a) + e2; full-tile (128-col) min per row;
    // ballot-compact capture of d2a <= tilemin + DELTA (ascending code order).
    // C/D layout (m89-verified): col = lane&15 (+n*16), row = lg*4 + j (+m*16)
    const int grow0 = m_base + rb + lg * 4;
    float e2v[8];
#pragma unroll
    for (int n = 0; n < 8; ++n) e2v[n] = e2[n_base + n * 16 + l15];

#pragma unroll
    for (int m = 0; m < 2; ++m) {
#pragma unroll
        for (int j = 0; j < 4; ++j) {
            int gr = grow0 + m * 16 + j;
            float x2v = x2[gr];
            float d2v[8];
            float mn = __builtin_inff();
#pragma unroll
            for (int n = 0; n < 8; ++n) {
                d2v[n] = (x2v - 2.0f * acc[m][n][j]) + e2v[n];
                mn = fminf(mn, d2v[n]);
            }
#pragma unroll
            for (int s = 1; s < 16; s <<= 1) mn = fminf(mn, __shfl_xor(mn, s));
            float thr = mn + DELTA;
            int base = 0;
#pragma unroll
            for (int n = 0; n < 8; ++n) {
                bool cap = d2v[n] <= thr;
                unsigned long long bal = __ballot(cap);
                unsigned bits = (unsigned)((bal >> (lg * 16)) & 0xFFFFull);
                int pos = base + __popc(bits & ((1u << l15) - 1u));
                if (cap && pos < CAP)
                    cands[(gr * 16 + nt) * CAP + pos] = (unsigned char)(n * 16 + l15);
                base += __popc(bits);
            }
            if (l15 == 0) {
                tilemin[gr * 16 + nt] = mn;
                counts[gr * 16 + nt] = (unsigned char)base;   // <= 128
            }
        }
    }
}

// ------- np-exact rescore: global tile filter + fused gather (1 wave/row) -----
__launch_bounds__(256, 4)
__global__ void vq_rescore(const float* __restrict__ x, const float* __restrict__ embed,
                           const float* __restrict__ e2, const float* __restrict__ x2,
                           const float* __restrict__ tilemin,
                           const unsigned char* __restrict__ counts,
                           const unsigned char* __restrict__ cands,
                           const float* __restrict__ es, const float* __restrict__ us,
                           float* __restrict__ out) {
    const int tid = threadIdx.x;
    const int r = blockIdx.x * 4 + (tid >> 6);
    const int lane = tid & 63;

    // global approx min over the 16 tile minima
    float gm = tilemin[r * 16 + (lane & 15)];
#pragma unroll
    for (int s = 1; s < 16; s <<= 1) gm = fminf(gm, __shfl_xor(gm, s));
    const float thr = gm + DELTA;

    float bv = __builtin_inff();
    int bi = 0x7FFFFFFF;
    const float x2v = x2[r];

    auto dot_d2 = [&](int code) -> float {
        float t = 0.0f;
#pragma unroll 8
        for (int k4 = 0; k4 < 64; ++k4) {                 // single chain, k ascending
            f32x4 a4 = *(const f32x4*)&x[r * D_DIM + k4 * 4];
            f32x4 e4 = *(const f32x4*)&embed[code * D_DIM + k4 * 4];
            t = __builtin_fmaf(a4[0], e4[0], t);
            t = __builtin_fmaf(a4[1], e4[1], t);
            t = __builtin_fmaf(a4[2], e4[2], t);
            t = __builtin_fmaf(a4[3], e4[3], t);
        }
        return (x2v - 2.0f * t) + e2[code];               // np op order
    };
    auto lexmin = [&](float d2, int code) {
        if (d2 < bv || (d2 == bv && code < bi)) { bv = d2; bi = code; }
    };

    unsigned long long ov[2];
#pragma unroll
    for (int p = 0; p < 2; ++p) {                         // 8 tiles per pass, 8 lanes/tile
        int t = (lane >> 3) + p * 8;
        float tmt = tilemin[r * 16 + t];
        int cnt = counts[r * 16 + t];
        bool q = (tmt <= thr);
        ov[p] = __ballot(q && cnt > CAP && (lane & 7) == 0);
        if (q && cnt <= CAP && (lane & 7) < cnt) {
            int code = t * 128 + (int)cands[r * 128 + p * 64 + lane];
            lexmin(dot_d2(code), code);
        }
    }
#pragma unroll
    for (int p = 0; p < 2; ++p) {                         // rare: rescan whole tile
        unsigned long long m = ov[p];
        while (m) {
            int b = __ffsll((unsigned long long)m) - 1;
            m &= m - 1;
            int t = (b >> 3) + p * 8;
#pragma unroll
            for (int q2 = 0; q2 < 2; ++q2) {
                int code = t * 128 + q2 * 64 + lane;
                lexmin(dot_d2(code), code);
            }
        }
    }
#pragma unroll
    for (int s = 1; s < 64; s <<= 1) {                    // 64-lane lex allreduce
        float ovv = __shfl_xor(bv, s);
        int oi = __shfl_xor(bi, s);
        if (ovv < bv || (ovv == bv && oi < bi)) { bv = ovv; bi = oi; }
    }
    if (lane == 0) out[r] = (float)bi;

    // fused gather: quantized[r] = es[bi]/max(us[bi],eps); 64 lanes x 4 cols
    float u = fmaxf(us[bi], VQ_EPS);
    f32x4 w = *(const f32x4*)&es[bi * D_DIM + lane * 4];
    f32x4 o;
#pragma unroll
    for (int j = 0; j < 4; ++j) o[j] = w[j] / u;          // IEEE div == np bitwise
    *(f32x4*)&out[N_ROWS + r * D_DIM + lane * 4] = o;
}

extern "C" void kernel_launch(void* const* d_in, const int* in_sizes, int n_in,
                              void* d_out, int out_size, void* d_ws, size_t ws_size,
                              hipStream_t stream) {
    const float* x = (const float*)d_in[0];               // [65536, 256]
    const float* es = (const float*)d_in[1];              // [2048, 256]
    const float* us = (const float*)d_in[2];              // [2048]
    float* out = (float*)d_out;

    char* w = (char*)d_ws;                                // total 15,998,976 B
    float* embed          = (float*)(w);                  //  2,097,152
    float* e2             = (float*)(w + 2097152);        //      8,192
    float* x2             = (float*)(w + 2105344);        //    262,144
    float* tilemin        = (float*)(w + 2367488);        //  4,194,304
    unsigned char* counts = (unsigned char*)(w + 6561792);//  1,048,576
    unsigned char* cands  = (unsigned char*)(w + 7610368);//  8,388,608 (CAP=8)

    hipLaunchKernelGGL(prep_embed, dim3(2048), dim3(256), 0, stream, es, us, embed);
    hipLaunchKernelGGL(prep_e2, dim3(128), dim3(256), 0, stream, embed, e2);
    hipLaunchKernelGGL(prep_x2, dim3(4096), dim3(256), 0, stream, x, x2);
    hipLaunchKernelGGL(vq_scan, dim3(8192), dim3(256), 0, stream,
                       x, embed, e2, x2, tilemin, counts, cands);
    hipLaunchKernelGGL(vq_rescore, dim3(16384), dim3(256), 0, stream,
                       x, embed, e2, x2, tilemin, counts, cands, es, us, out);
}